// Round 1
// baseline (42.323 us; speedup 1.0000x reference)
//
#include <hip/hip_runtime.h>
#include <math.h>

#define OBS 2264
#define ACT 32
#define HID 4096
#define VOX 216
#define PRE (OBS - VOX)   // 2048

// ---------------------------------------------------------------------------
// K1: 6x Conv3d(1,1,3,SAME)+ReLU on the 6x6x6 voxel tail, then input
// normalization -> u[2264] in workspace. Single block, 256 threads.
// lax.conv_general_dilated = cross-correlation (no kernel flip), pad=1.
// ---------------------------------------------------------------------------
__global__ __launch_bounds__(256) void conv_norm_kernel(
    const float* __restrict__ x,
    const float* __restrict__ cw0, const float* __restrict__ cb0,
    const float* __restrict__ cw1, const float* __restrict__ cb1,
    const float* __restrict__ cw2, const float* __restrict__ cb2,
    const float* __restrict__ cw3, const float* __restrict__ cb3,
    const float* __restrict__ cw4, const float* __restrict__ cb4,
    const float* __restrict__ cw5, const float* __restrict__ cb5,
    const float* __restrict__ in_shift, const float* __restrict__ in_scale,
    float* __restrict__ u)
{
    __shared__ float vb[2][VOX];
    const int tid = threadIdx.x;

    if (tid < VOX) vb[0][tid] = x[PRE + tid];
    __syncthreads();

    const float* ws[6] = {cw0, cw1, cw2, cw3, cw4, cw5};
    const float* bs[6] = {cb0, cb1, cb2, cb3, cb4, cb5};

    int cur = 0;
    for (int l = 0; l < 6; ++l) {
        float acc = 0.f;
        if (tid < VOX) {
            const int d = tid / 36;
            const int h = (tid / 6) % 6;
            const int w = tid % 6;
            const float* k = ws[l];
            acc = bs[l][0];
            #pragma unroll
            for (int kd = 0; kd < 3; ++kd) {
                const int dd = d + kd - 1;
                if (dd < 0 || dd > 5) continue;
                #pragma unroll
                for (int kh = 0; kh < 3; ++kh) {
                    const int hh = h + kh - 1;
                    if (hh < 0 || hh > 5) continue;
                    #pragma unroll
                    for (int kw = 0; kw < 3; ++kw) {
                        const int ww = w + kw - 1;
                        if (ww < 0 || ww > 5) continue;
                        acc += k[kd * 9 + kh * 3 + kw] * vb[cur][dd * 36 + hh * 6 + ww];
                    }
                }
            }
            acc = fmaxf(acc, 0.f);
            vb[cur ^ 1][tid] = acc;
        }
        cur ^= 1;
        __syncthreads();
    }
    // after 6 layers result is in vb[0] (cur toggled 6 times -> cur==0)

    for (int i = tid; i < OBS; i += 256) {
        const float val = (i < PRE) ? x[i] : vb[cur][i - PRE];
        u[i] = (val - in_shift[i]) / (in_scale[i] + 1e-8f);
    }
}

// ---------------------------------------------------------------------------
// GEMV: one block (256 threads) per output row. W row-major [rows, NIN],
// float4 loads (NIN divisible by 4, rows 16B-aligned).
// ---------------------------------------------------------------------------
template<int NIN, bool DO_TANH>
__global__ __launch_bounds__(256) void gemv_kernel(
    const float* __restrict__ W, const float* __restrict__ b,
    const float* __restrict__ u, float* __restrict__ out)
{
    constexpr int N4 = NIN / 4;
    const int row = blockIdx.x;
    const int tid = threadIdx.x;
    const float4* __restrict__ Wr = reinterpret_cast<const float4*>(W + (size_t)row * NIN);
    const float4* __restrict__ u4 = reinterpret_cast<const float4*>(u);

    float acc = 0.f;
    for (int j = tid; j < N4; j += 256) {
        const float4 wv = Wr[j];
        const float4 uv = u4[j];
        acc += wv.x * uv.x + wv.y * uv.y + wv.z * uv.z + wv.w * uv.w;
    }
    #pragma unroll
    for (int off = 32; off > 0; off >>= 1) acc += __shfl_down(acc, off, 64);

    __shared__ float part[4];
    if ((tid & 63) == 0) part[tid >> 6] = acc;
    __syncthreads();
    if (tid == 0) {
        float s = part[0] + part[1] + part[2] + part[3] + b[row];
        out[row] = DO_TANH ? tanhf(s) : s;
    }
}

// ---------------------------------------------------------------------------
// K4: final GEMV [32,4096] + affine output transform.
// ---------------------------------------------------------------------------
__global__ __launch_bounds__(256) void gemv_out_kernel(
    const float* __restrict__ W, const float* __restrict__ b,
    const float* __restrict__ u,
    const float* __restrict__ oscale, const float* __restrict__ oshift,
    float* __restrict__ out)
{
    constexpr int N4 = HID / 4;
    const int row = blockIdx.x;
    const int tid = threadIdx.x;
    const float4* __restrict__ Wr = reinterpret_cast<const float4*>(W + (size_t)row * HID);
    const float4* __restrict__ u4 = reinterpret_cast<const float4*>(u);

    float acc = 0.f;
    for (int j = tid; j < N4; j += 256) {
        const float4 wv = Wr[j];
        const float4 uv = u4[j];
        acc += wv.x * uv.x + wv.y * uv.y + wv.z * uv.z + wv.w * uv.w;
    }
    #pragma unroll
    for (int off = 32; off > 0; off >>= 1) acc += __shfl_down(acc, off, 64);

    __shared__ float part[4];
    if ((tid & 63) == 0) part[tid >> 6] = acc;
    __syncthreads();
    if (tid == 0) {
        float s = part[0] + part[1] + part[2] + part[3] + b[row];
        out[row] = s * oscale[row] + oshift[row];
    }
}

extern "C" void kernel_launch(void* const* d_in, const int* in_sizes, int n_in,
                              void* d_out, int out_size, void* d_ws, size_t ws_size,
                              hipStream_t stream) {
    const float* x = (const float*)d_in[0];

    // setup_inputs() dict order interleaves cw_i/cb_i; detect defensively.
    const float* cw[6];
    const float* cb[6];
    if (in_sizes[2] == 1) {           // interleaved: x, cw0, cb0, cw1, cb1, ...
        for (int i = 0; i < 6; ++i) {
            cw[i] = (const float*)d_in[1 + 2 * i];
            cb[i] = (const float*)d_in[2 + 2 * i];
        }
    } else {                          // grouped: x, cw0..cw5, cb0..cb5
        for (int i = 0; i < 6; ++i) {
            cw[i] = (const float*)d_in[1 + i];
            cb[i] = (const float*)d_in[7 + i];
        }
    }
    const float* W0       = (const float*)d_in[13];
    const float* b0       = (const float*)d_in[14];
    const float* W1       = (const float*)d_in[15];
    const float* b1       = (const float*)d_in[16];
    const float* W2       = (const float*)d_in[17];
    const float* b2       = (const float*)d_in[18];
    const float* in_shift = (const float*)d_in[19];
    const float* in_scale = (const float*)d_in[20];
    const float* oshift   = (const float*)d_in[21];
    const float* oscale   = (const float*)d_in[22];

    float* ws = (float*)d_ws;
    float* u  = ws;            // [0, 2264)   (pad to 2304)
    float* h0 = ws + 2304;     // [2304, 6400)
    float* h1 = ws + 6400;     // [6400, 10496)
    float* y  = (float*)d_out;

    conv_norm_kernel<<<1, 256, 0, stream>>>(
        x, cw[0], cb[0], cw[1], cb[1], cw[2], cb[2],
        cw[3], cb[3], cw[4], cb[4], cw[5], cb[5],
        in_shift, in_scale, u);

    gemv_kernel<OBS, true><<<HID, 256, 0, stream>>>(W0, b0, u, h0);
    gemv_kernel<HID, true><<<HID, 256, 0, stream>>>(W1, b1, h0, h1);
    gemv_out_kernel<<<ACT, 256, 0, stream>>>(W2, b2, h1, oscale, oshift, y);
}